// Round 1
// baseline (461.255 us; speedup 1.0000x reference)
//
#include <hip/hip_runtime.h>
#include <math.h>

#define BB 1024   // batch
#define VV 256    // variables
#define KK 64     // categories
#define MM 32     // input nodes per variable
#define N0 8192   // input nodes
#define CC 32     // sum-node children

// ---------------------------------------------------------------------------
// Kernel 0: transpose x [B,V] -> xt [V,B] so the input-layer batch loop reads
// coalesced.
// ---------------------------------------------------------------------------
__global__ void k_transpose_x(const int* __restrict__ x, int* __restrict__ xt) {
    int idx = blockIdx.x * blockDim.x + threadIdx.x;  // over V*B
    int v = idx >> 10;       // / B (B=1024)
    int b = idx & (BB - 1);
    xt[idx] = x[b * VV + v];
}

// ---------------------------------------------------------------------------
// Kernel 1: input layer. One block per input node i (0..N0-1).
// nm[(1+i)*B + b] = log_softmax(in_logits[i])[ xt[var(i)*B + b] ]
// Wave 0 (64 lanes == K) computes the log-softmax row into LDS, then all 256
// threads stream the batch.
// ---------------------------------------------------------------------------
__global__ void k_input_layer(const float* __restrict__ logits,
                              const int* __restrict__ xt,
                              float* __restrict__ nm) {
    int i = blockIdx.x;
    int t = threadIdx.x;
    __shared__ float lp[KK];
    if (t < KK) {
        float l = logits[(size_t)i * KK + t];
        float m = l;
        #pragma unroll
        for (int d = 32; d; d >>= 1) m = fmaxf(m, __shfl_xor(m, d));
        float s = expf(l - m);
        #pragma unroll
        for (int d = 32; d; d >>= 1) s += __shfl_xor(s, d);
        lp[t] = l - m - logf(s);
    }
    __syncthreads();
    int v = i >> 5;  // i / M
    const int* xv = xt + v * BB;
    float* o = nm + (size_t)(1 + i) * BB;
    for (int b = t; b < BB; b += blockDim.x) o[b] = lp[xv[b]];
}

// ---------------------------------------------------------------------------
// Kernel 2: product layer. One block per element e (0..E-1; element id e+1).
// em[e*B + b] = nm[pids[e][0]*B + b] + nm[pids[e][1]*B + b]
// pids hold global node ids (>=1), batch loop coalesced.
// ---------------------------------------------------------------------------
__global__ void k_prod_layer(const float* __restrict__ nm,
                             const int* __restrict__ pids,
                             float* __restrict__ em) {
    int e = blockIdx.x;
    int p0 = pids[e * 2 + 0];
    int p1 = pids[e * 2 + 1];
    const float* r0 = nm + (size_t)p0 * BB;
    const float* r1 = nm + (size_t)p1 * BB;
    float* o = em + (size_t)e * BB;
    for (int b = threadIdx.x; b < BB; b += blockDim.x) o[b] = r0[b] + r1[b];
}

// ---------------------------------------------------------------------------
// Kernel 3: sum layer. One block per sum node s.
// out[s*B + b] = logsumexp_c( em[(cids[s][c]-1)*B + b] + log_softmax(w[s])[c] )
// Half-wave (32 lanes == C) computes normalized log-weights + child ids into
// LDS; each thread then does a full 32-way logsumexp per batch element with
// the 32 values held in registers (single gather pass).
// ---------------------------------------------------------------------------
__global__ void k_sum_layer(const float* __restrict__ em,
                            const int* __restrict__ cids,
                            const float* __restrict__ w,
                            float* __restrict__ out) {
    int s = blockIdx.x;
    int t = threadIdx.x;
    __shared__ float slw[CC];
    __shared__ int scid[CC];
    if (t < CC) {
        float lw = w[s * CC + t];
        float m = lw;
        #pragma unroll
        for (int d = 16; d; d >>= 1) m = fmaxf(m, __shfl_xor(m, d, 32));
        float su = expf(lw - m);
        #pragma unroll
        for (int d = 16; d; d >>= 1) su += __shfl_xor(su, d, 32);
        slw[t] = lw - m - logf(su);
        scid[t] = cids[s * CC + t] - 1;  // element id -> em row
    }
    __syncthreads();
    float* o = out + (size_t)s * BB;
    for (int b = t; b < BB; b += blockDim.x) {
        float v[CC];
        float mx = -INFINITY;
        #pragma unroll
        for (int c = 0; c < CC; ++c) {
            v[c] = em[(size_t)scid[c] * BB + b] + slw[c];
            mx = fmaxf(mx, v[c]);
        }
        float su = 0.f;
        #pragma unroll
        for (int c = 0; c < CC; ++c) su += expf(v[c] - mx);
        o[b] = mx + logf(su);
    }
}

// ---------------------------------------------------------------------------
// Launch: nm rows are global node ids 0..15360 (row 0 never referenced by
// pids, left unwritten). em reused across layers (max E = 8192 rows).
// Layer output global-id starts: S1=8193, S2=12289, S3=14337; root -> d_out.
// ---------------------------------------------------------------------------
extern "C" void kernel_launch(void* const* d_in, const int* in_sizes, int n_in,
                              void* d_out, int out_size, void* d_ws, size_t ws_size,
                              hipStream_t stream) {
    const int*   x         = (const int*)  d_in[0];
    const float* in_logits = (const float*)d_in[1];
    const float* w1        = (const float*)d_in[2];
    const float* w2        = (const float*)d_in[3];
    const float* w3        = (const float*)d_in[4];
    const float* w4        = (const float*)d_in[5];
    const int*   pids1     = (const int*)  d_in[6];
    const int*   pids2     = (const int*)  d_in[7];
    const int*   pids3     = (const int*)  d_in[8];
    const int*   pids4     = (const int*)  d_in[9];
    const int*   cids1     = (const int*)  d_in[10];
    const int*   cids2     = (const int*)  d_in[11];
    const int*   cids3     = (const int*)  d_in[12];
    const int*   cids4     = (const int*)  d_in[13];
    float* out = (float*)d_out;

    float* nm = (float*)d_ws;                       // 15361 * 1024 floats
    float* em = nm + (size_t)15361 * BB;            //  8192 * 1024 floats
    int*   xt = (int*)(em + (size_t)8192 * BB);     //   256 * 1024 ints

    k_transpose_x<<<(VV * BB) / 256, 256, 0, stream>>>(x, xt);
    k_input_layer<<<N0, 256, 0, stream>>>(in_logits, xt, nm);

    // layer pair 1: E=8192 -> S=4096 (global ids 8193..12288)
    k_prod_layer<<<8192, 256, 0, stream>>>(nm, pids1, em);
    k_sum_layer <<<4096, 256, 0, stream>>>(em, cids1, w1, nm + (size_t)8193 * BB);
    // layer pair 2: E=4096 -> S=2048 (ids 12289..14336)
    k_prod_layer<<<4096, 256, 0, stream>>>(nm, pids2, em);
    k_sum_layer <<<2048, 256, 0, stream>>>(em, cids2, w2, nm + (size_t)12289 * BB);
    // layer pair 3: E=2048 -> S=1024 (ids 14337..15360)
    k_prod_layer<<<2048, 256, 0, stream>>>(nm, pids3, em);
    k_sum_layer <<<1024, 256, 0, stream>>>(em, cids3, w3, nm + (size_t)14337 * BB);
    // layer pair 4: E=1024 -> root (direct to output, 1024 floats)
    k_prod_layer<<<1024, 256, 0, stream>>>(nm, pids4, em);
    k_sum_layer <<<   1, 256, 0, stream>>>(em, cids4, w4, out);
}

// Round 2
// 239.570 us; speedup vs baseline: 1.9254x; 1.9254x over previous
//
#include <hip/hip_runtime.h>
#include <math.h>

#define BB 1024   // batch
#define VV 256    // variables
#define KK 64     // categories
#define N0 8192   // input nodes
#define CC 32     // sum-node children
#define W  128    // batch chunk width = B / 8 XCDs; 8192 rows * 512B = 4MB = per-XCD L2

// ---------------------------------------------------------------------------
// transpose x [B,V] -> xt [V,B]  (1 MB, negligible)
// ---------------------------------------------------------------------------
__global__ void k_transpose_x(const int* __restrict__ x, int* __restrict__ xt) {
    int idx = blockIdx.x * blockDim.x + threadIdx.x;
    int v = idx >> 10;
    int b = idx & (BB - 1);
    xt[idx] = x[b * VV + v];
}

// ---------------------------------------------------------------------------
// log-softmax rows of in_logits -> lp [N0][K]. One wave per row (K=64).
// ---------------------------------------------------------------------------
__global__ void __launch_bounds__(256) k_logsoftmax(const float* __restrict__ logits,
                                                    float* __restrict__ lp) {
    int row = blockIdx.x * 4 + (threadIdx.x >> 6);  // 4 waves/block, 1 row/wave
    int k = threadIdx.x & 63;
    float l = logits[(size_t)row * KK + k];
    float m = l;
    #pragma unroll
    for (int d = 32; d; d >>= 1) m = fmaxf(m, __shfl_xor(m, d));
    float s = expf(l - m);
    #pragma unroll
    for (int d = 32; d; d >>= 1) s += __shfl_xor(s, d);
    lp[(size_t)row * KK + k] = l - m - logf(s);
}

// ---------------------------------------------------------------------------
// input gather: block g -> chunk (g&7) maps to one XCD; 8 input nodes per
// block. nm[(1+i)*B + b] = lp[i][ xt[var(i)*B + b] ]
// ---------------------------------------------------------------------------
__global__ void __launch_bounds__(W) k_input_gather(const float* __restrict__ lp,
                                                    const int* __restrict__ xt,
                                                    float* __restrict__ nm) {
    int g = blockIdx.x;
    int chunk = g & 7;
    int i0 = (g >> 3) * 8;
    int b = chunk * W + threadIdx.x;
    int v = i0 >> 5;                 // same variable for all 8 nodes (8 | 32)
    int xv = xt[v * BB + b];
    #pragma unroll
    for (int j = 0; j < 8; ++j) {
        int i = i0 + j;
        nm[(size_t)(1 + i) * BB + b] = lp[(size_t)i * KK + xv];
    }
}

// ---------------------------------------------------------------------------
// product layer: block g -> chunk (g&7), 8 elements per block.
// em[e*B+b] = nm[p0*B+b] + nm[p1*B+b]
// ---------------------------------------------------------------------------
__global__ void __launch_bounds__(W) k_prod_layer(const float* __restrict__ nm,
                                                  const int* __restrict__ pids,
                                                  float* __restrict__ em) {
    int g = blockIdx.x;
    int chunk = g & 7;
    int e0 = (g >> 3) * 8;
    int b = chunk * W + threadIdx.x;
    #pragma unroll
    for (int j = 0; j < 8; ++j) {
        int e = e0 + j;
        int p0 = pids[e * 2 + 0];
        int p1 = pids[e * 2 + 1];
        em[(size_t)e * BB + b] = nm[(size_t)p0 * BB + b] + nm[(size_t)p1 * BB + b];
    }
}

// ---------------------------------------------------------------------------
// sum layer: block g -> chunk (g&7), one sum node per block, 128 batch cols.
// out[s*B+b] = logsumexp_c( em[(cids[s][c]-1)*B+b] + log_softmax(w[s])[c] )
// ---------------------------------------------------------------------------
__global__ void __launch_bounds__(W) k_sum_layer(const float* __restrict__ em,
                                                 const int* __restrict__ cids,
                                                 const float* __restrict__ w,
                                                 float* __restrict__ out) {
    int g = blockIdx.x;
    int chunk = g & 7;
    int s = g >> 3;
    int t = threadIdx.x;
    __shared__ float slw[CC];
    __shared__ int scid[CC];
    if (t < CC) {
        float lw = w[s * CC + t];
        float m = lw;
        #pragma unroll
        for (int d = 16; d; d >>= 1) m = fmaxf(m, __shfl_xor(m, d, 32));
        float su = expf(lw - m);
        #pragma unroll
        for (int d = 16; d; d >>= 1) su += __shfl_xor(su, d, 32);
        slw[t] = lw - m - logf(su);
        scid[t] = cids[s * CC + t] - 1;
    }
    __syncthreads();
    int b = chunk * W + t;
    float v[CC];
    float mx = -INFINITY;
    #pragma unroll
    for (int c = 0; c < CC; ++c) {
        v[c] = em[(size_t)scid[c] * BB + b] + slw[c];
        mx = fmaxf(mx, v[c]);
    }
    float su = 0.f;
    #pragma unroll
    for (int c = 0; c < CC; ++c) su += expf(v[c] - mx);
    out[(size_t)s * BB + b] = mx + logf(su);
}

// ---------------------------------------------------------------------------
// Launch. nm rows = global node ids 0..15360 (row 0 never referenced).
// lp aliases the em buffer (only live before prod layer 1 overwrites it).
// ---------------------------------------------------------------------------
extern "C" void kernel_launch(void* const* d_in, const int* in_sizes, int n_in,
                              void* d_out, int out_size, void* d_ws, size_t ws_size,
                              hipStream_t stream) {
    const int*   x         = (const int*)  d_in[0];
    const float* in_logits = (const float*)d_in[1];
    const float* w1        = (const float*)d_in[2];
    const float* w2        = (const float*)d_in[3];
    const float* w3        = (const float*)d_in[4];
    const float* w4        = (const float*)d_in[5];
    const int*   pids1     = (const int*)  d_in[6];
    const int*   pids2     = (const int*)  d_in[7];
    const int*   pids3     = (const int*)  d_in[8];
    const int*   pids4     = (const int*)  d_in[9];
    const int*   cids1     = (const int*)  d_in[10];
    const int*   cids2     = (const int*)  d_in[11];
    const int*   cids3     = (const int*)  d_in[12];
    const int*   cids4     = (const int*)  d_in[13];
    float* out = (float*)d_out;

    float* nm = (float*)d_ws;                       // 15361 * 1024 floats
    float* em = nm + (size_t)15361 * BB;            //  8192 * 1024 floats
    int*   xt = (int*)(em + (size_t)8192 * BB);     //   256 * 1024 ints
    float* lp = em;                                 // 8192*64 floats, aliased

    k_transpose_x <<<(VV * BB) / 256, 256, 0, stream>>>(x, xt);
    k_logsoftmax  <<<N0 / 4, 256, 0, stream>>>(in_logits, lp);
    k_input_gather<<<(N0 / 8) * 8, W, 0, stream>>>(lp, xt, nm);

    // layer pair 1: E=8192 -> S=4096 (global ids 8193..12288)
    k_prod_layer<<<8192, W, 0, stream>>>(nm, pids1, em);
    k_sum_layer <<<4096 * 8, W, 0, stream>>>(em, cids1, w1, nm + (size_t)8193 * BB);
    // layer pair 2: E=4096 -> S=2048 (ids 12289..14336)
    k_prod_layer<<<4096, W, 0, stream>>>(nm, pids2, em);
    k_sum_layer <<<2048 * 8, W, 0, stream>>>(em, cids2, w2, nm + (size_t)12289 * BB);
    // layer pair 3: E=2048 -> S=1024 (ids 14337..15360)
    k_prod_layer<<<2048, W, 0, stream>>>(nm, pids3, em);
    k_sum_layer <<<1024 * 8, W, 0, stream>>>(em, cids3, w3, nm + (size_t)14337 * BB);
    // layer pair 4: E=1024 -> root (direct to d_out, 1024 floats)
    k_prod_layer<<<1024, W, 0, stream>>>(nm, pids4, em);
    k_sum_layer <<<1 * 8, W, 0, stream>>>(em, cids4, w4, out);
}

// Round 3
// 200.039 us; speedup vs baseline: 2.3058x; 1.1976x over previous
//
#include <hip/hip_runtime.h>
#include <math.h>

#define BB 1024   // batch
#define VV 256    // variables
#define KK 64     // categories
#define N0 8192   // input nodes
#define CC 32     // sum-node children
#define W  128    // batch chunk width = B / 8 XCDs; 8192 rows * 512B = 4MB = per-XCD L2

// ---------------------------------------------------------------------------
// transpose x [B,V] -> xt [V,B]
// ---------------------------------------------------------------------------
__global__ void k_transpose_x(const int* __restrict__ x, int* __restrict__ xt) {
    int idx = blockIdx.x * blockDim.x + threadIdx.x;
    int v = idx >> 10;
    int b = idx & (BB - 1);
    xt[idx] = x[b * VV + v];
}

// ---------------------------------------------------------------------------
// log-softmax rows of in_logits -> lp [N0][K]. One wave per row (K=64).
// ---------------------------------------------------------------------------
__global__ void __launch_bounds__(256) k_logsoftmax(const float* __restrict__ logits,
                                                    float* __restrict__ lp) {
    int row = blockIdx.x * 4 + (threadIdx.x >> 6);
    int k = threadIdx.x & 63;
    float l = logits[(size_t)row * KK + k];
    float m = l;
    #pragma unroll
    for (int d = 32; d; d >>= 1) m = fmaxf(m, __shfl_xor(m, d));
    float s = __expf(l - m);
    #pragma unroll
    for (int d = 32; d; d >>= 1) s += __shfl_xor(s, d);
    lp[(size_t)row * KK + k] = l - m - __logf(s);
}

// ---------------------------------------------------------------------------
// input gather: block g -> chunk (g&7); 8 input nodes per block, 1 col/thread.
// ---------------------------------------------------------------------------
__global__ void __launch_bounds__(W) k_input_gather(const float* __restrict__ lp,
                                                    const int* __restrict__ xt,
                                                    float* __restrict__ nm) {
    int g = blockIdx.x;
    int chunk = g & 7;
    int i0 = (g >> 3) * 8;
    int b = chunk * W + threadIdx.x;
    int v = i0 >> 5;                 // same variable for all 8 nodes (8 | 32)
    int xv = xt[v * BB + b];
    #pragma unroll
    for (int j = 0; j < 8; ++j) {
        int i = i0 + j;
        nm[(size_t)(1 + i) * BB + b] = lp[(size_t)i * KK + xv];
    }
}

// ---------------------------------------------------------------------------
// product layer: block = 128 threads = 4 elements x 32 lanes, float4 cols.
// em[e*B + b..b+3] = nm[p0*B + b..] + nm[p1*B + b..]
// ---------------------------------------------------------------------------
__global__ void __launch_bounds__(W) k_prod_layer(const float* __restrict__ nm,
                                                  const int* __restrict__ pids,
                                                  float* __restrict__ em) {
    int g = blockIdx.x;
    int chunk = g & 7;
    int sub = threadIdx.x >> 5;
    int lane = threadIdx.x & 31;
    int e = (g >> 3) * 4 + sub;
    int p0 = pids[e * 2 + 0];
    int p1 = pids[e * 2 + 1];
    int b = chunk * W + lane * 4;
    const float4 a = *(const float4*)(nm + (size_t)p0 * BB + b);
    const float4 c = *(const float4*)(nm + (size_t)p1 * BB + b);
    float4 o;
    o.x = a.x + c.x; o.y = a.y + c.y; o.z = a.z + c.z; o.w = a.w + c.w;
    *(float4*)(em + (size_t)e * BB + b) = o;
}

// ---------------------------------------------------------------------------
// sum layer: block = 128 threads = 4 sum nodes x 32 lanes, float4 cols.
// out[s*B+b] = logsumexp_c( em[(cids[s][c]-1)*B+b] + log_softmax(w[s])[c] )
// ---------------------------------------------------------------------------
__global__ void __launch_bounds__(W) k_sum_layer(const float* __restrict__ em,
                                                 const int* __restrict__ cids,
                                                 const float* __restrict__ w,
                                                 float* __restrict__ out,
                                                 int S) {
    int g = blockIdx.x;
    int chunk = g & 7;
    int sub = threadIdx.x >> 5;
    int lane = threadIdx.x & 31;
    int s = (g >> 3) * 4 + sub;
    __shared__ float slw[4][CC];
    __shared__ int scid[4][CC];
    bool valid = s < S;
    if (valid) {
        float lw = w[s * CC + lane];
        float m = lw;
        #pragma unroll
        for (int d = 16; d; d >>= 1) m = fmaxf(m, __shfl_xor(m, d, 32));
        float su = __expf(lw - m);
        #pragma unroll
        for (int d = 16; d; d >>= 1) su += __shfl_xor(su, d, 32);
        slw[sub][lane] = lw - m - __logf(su);
        scid[sub][lane] = cids[s * CC + lane] - 1;
    }
    __syncthreads();
    if (!valid) return;
    int b = chunk * W + lane * 4;
    float4 v[CC];
    float4 mx = {-INFINITY, -INFINITY, -INFINITY, -INFINITY};
    #pragma unroll
    for (int c = 0; c < CC; ++c) {
        float4 t4 = *(const float4*)(em + (size_t)scid[sub][c] * BB + b);
        float lw = slw[sub][c];
        t4.x += lw; t4.y += lw; t4.z += lw; t4.w += lw;
        v[c] = t4;
        mx.x = fmaxf(mx.x, t4.x); mx.y = fmaxf(mx.y, t4.y);
        mx.z = fmaxf(mx.z, t4.z); mx.w = fmaxf(mx.w, t4.w);
    }
    float4 su = {0.f, 0.f, 0.f, 0.f};
    #pragma unroll
    for (int c = 0; c < CC; ++c) {
        su.x += __expf(v[c].x - mx.x);
        su.y += __expf(v[c].y - mx.y);
        su.z += __expf(v[c].z - mx.z);
        su.w += __expf(v[c].w - mx.w);
    }
    float4 o;
    o.x = mx.x + __logf(su.x);
    o.y = mx.y + __logf(su.y);
    o.z = mx.z + __logf(su.z);
    o.w = mx.w + __logf(su.w);
    *(float4*)(out + (size_t)s * BB + b) = o;
}

// ---------------------------------------------------------------------------
// Launch. nm rows = global node ids 0..15360 (row 0 never referenced).
// lp aliases the em buffer (only live before prod layer 1 overwrites it).
// ---------------------------------------------------------------------------
extern "C" void kernel_launch(void* const* d_in, const int* in_sizes, int n_in,
                              void* d_out, int out_size, void* d_ws, size_t ws_size,
                              hipStream_t stream) {
    const int*   x         = (const int*)  d_in[0];
    const float* in_logits = (const float*)d_in[1];
    const float* w1        = (const float*)d_in[2];
    const float* w2        = (const float*)d_in[3];
    const float* w3        = (const float*)d_in[4];
    const float* w4        = (const float*)d_in[5];
    const int*   pids1     = (const int*)  d_in[6];
    const int*   pids2     = (const int*)  d_in[7];
    const int*   pids3     = (const int*)  d_in[8];
    const int*   pids4     = (const int*)  d_in[9];
    const int*   cids1     = (const int*)  d_in[10];
    const int*   cids2     = (const int*)  d_in[11];
    const int*   cids3     = (const int*)  d_in[12];
    const int*   cids4     = (const int*)  d_in[13];
    float* out = (float*)d_out;

    float* nm = (float*)d_ws;                       // 15361 * 1024 floats
    float* em = nm + (size_t)15361 * BB;            //  8192 * 1024 floats
    int*   xt = (int*)(em + (size_t)8192 * BB);     //   256 * 1024 ints
    float* lp = em;                                 // 8192*64 floats, aliased

    k_transpose_x <<<(VV * BB) / 256, 256, 0, stream>>>(x, xt);
    k_logsoftmax  <<<N0 / 4, 256, 0, stream>>>(in_logits, lp);
    k_input_gather<<<(N0 / 8) * 8, W, 0, stream>>>(lp, xt, nm);

    // layer pair 1: E=8192 -> S=4096 (global ids 8193..12288)
    k_prod_layer<<<(8192 / 4) * 8, W, 0, stream>>>(nm, pids1, em);
    k_sum_layer <<<(4096 / 4) * 8, W, 0, stream>>>(em, cids1, w1, nm + (size_t)8193 * BB, 4096);
    // layer pair 2: E=4096 -> S=2048 (ids 12289..14336)
    k_prod_layer<<<(4096 / 4) * 8, W, 0, stream>>>(nm, pids2, em);
    k_sum_layer <<<(2048 / 4) * 8, W, 0, stream>>>(em, cids2, w2, nm + (size_t)12289 * BB, 2048);
    // layer pair 3: E=2048 -> S=1024 (ids 14337..15360)
    k_prod_layer<<<(2048 / 4) * 8, W, 0, stream>>>(nm, pids3, em);
    k_sum_layer <<<(1024 / 4) * 8, W, 0, stream>>>(em, cids3, w3, nm + (size_t)14337 * BB, 1024);
    // layer pair 4: E=1024 -> root (direct to d_out, 1024 floats)
    k_prod_layer<<<(1024 / 4) * 8, W, 0, stream>>>(nm, pids4, em);
    k_sum_layer <<<1 * 8, W, 0, stream>>>(em, cids4, w4, out, 1);
}